// Round 4
// baseline (18.414 us; speedup 1.0000x reference)
//
#include <hip/hip_runtime.h>

// Controlled target rotation, D=2, control=qubit0 (mask N/2), target=qubit1 (mask N/4).
// Harness output buffer: N float32 = REAL PART of the complex64 state only
// (complex64 reference degraded via astype(float32) on the harness side).
//   control clear (i < N/2): out[i] = xr[i]
//   control set:             out[i] = c*xr[i] + s*xi[i ^ (N/4)]
//   with c = cos(a/2), s = sin(a/2), a = angle[0].
// Note: for i in the upper half, the partner i^(N/4) is also in the upper half,
// so xi is only ever read on [N/2, N).

__global__ __launch_bounds__(256) void crx_real_kernel(
    const float* __restrict__ xr,
    const float* __restrict__ xi,
    const float* __restrict__ angle,
    float* __restrict__ out,   // N float32 (real part)
    unsigned int n)            // n = N complex elements
{
    const unsigned int cmask = n >> 1;   // control-bit mask
    const unsigned int tmask = n >> 2;   // target-bit mask

    unsigned int t = blockIdx.x * blockDim.x + threadIdx.x;
    unsigned int i0 = t * 4u;            // 4 consecutive elements per thread
    if (i0 >= n) return;

    float4 vr = *reinterpret_cast<const float4*>(xr + i0);
    float4 o;

    if (i0 & cmask) {
        float half_a = 0.5f * angle[0];
        float s = sinf(half_a);
        float c = cosf(half_a);
        float4 pi_ = *reinterpret_cast<const float4*>(xi + (i0 ^ tmask));
        o.x = fmaf(c, vr.x, s * pi_.x);
        o.y = fmaf(c, vr.y, s * pi_.y);
        o.z = fmaf(c, vr.z, s * pi_.z);
        o.w = fmaf(c, vr.w, s * pi_.w);
    } else {
        o = vr;
    }

    *reinterpret_cast<float4*>(out + i0) = o;
}

extern "C" void kernel_launch(void* const* d_in, const int* in_sizes, int n_in,
                              void* d_out, int out_size, void* d_ws, size_t ws_size,
                              hipStream_t stream) {
    const float* xr    = (const float*)d_in[0];
    const float* xi    = (const float*)d_in[1];
    const float* angle = (const float*)d_in[2];
    float* out = (float*)d_out;

    unsigned int n = (unsigned int)in_sizes[0];   // N = 2^23 complex elements
    unsigned int nthreads = n / 4u;
    unsigned int block = 256u;
    unsigned int grid = (nthreads + block - 1u) / block;

    crx_real_kernel<<<grid, block, 0, stream>>>(xr, xi, angle, out, n);
}

// Round 6
// 17.694 us; speedup vs baseline: 1.0407x; 1.0407x over previous
//
#include <hip/hip_runtime.h>

// Controlled target rotation, D=2, control=qubit0 (mask N/2), target=qubit1 (mask N/4).
// Output buffer: N float32 = REAL part of the complex64 state.
//   control clear (i < N/2): out[i] = xr[i]
//   control set:             out[i] = c*xr[i] + s*xi[i ^ (N/4)]
//   c = cos(a/2), s = sin(a/2), a = angle[0].
// Pure streaming (zero reuse) -> grid-stride @ 2048 blocks + non-temporal ld/st.

typedef float fvec4 __attribute__((ext_vector_type(4)));  // native vector: OK for nontemporal builtins

__global__ __launch_bounds__(256) void crx_real_kernel(
    const float* __restrict__ xr,
    const float* __restrict__ xi,
    const float* __restrict__ angle,
    float* __restrict__ out,   // N float32 (real part)
    unsigned int n4)           // number of float4 chunks = N/4
{
    const unsigned int cmask4 = n4 >> 1;   // control-bit mask, float4 units
    const unsigned int tmask4 = n4 >> 2;   // target-bit mask, float4 units

    float half_a = 0.5f * angle[0];
    float s = sinf(half_a);
    float c = cosf(half_a);

    const fvec4* xr4 = reinterpret_cast<const fvec4*>(xr);
    const fvec4* xi4 = reinterpret_cast<const fvec4*>(xi);
    fvec4* out4 = reinterpret_cast<fvec4*>(out);

    unsigned int stride = gridDim.x * blockDim.x;
    for (unsigned int idx = blockIdx.x * blockDim.x + threadIdx.x;
         idx < n4; idx += stride) {
        fvec4 vr = __builtin_nontemporal_load(xr4 + idx);
        fvec4 o;
        if (idx & cmask4) {   // wave-uniform: quarters are >> wave span
            fvec4 pi_ = __builtin_nontemporal_load(xi4 + (idx ^ tmask4));
            o.x = fmaf(c, vr.x, s * pi_.x);
            o.y = fmaf(c, vr.y, s * pi_.y);
            o.z = fmaf(c, vr.z, s * pi_.z);
            o.w = fmaf(c, vr.w, s * pi_.w);
        } else {
            o = vr;
        }
        __builtin_nontemporal_store(o, out4 + idx);
    }
}

extern "C" void kernel_launch(void* const* d_in, const int* in_sizes, int n_in,
                              void* d_out, int out_size, void* d_ws, size_t ws_size,
                              hipStream_t stream) {
    const float* xr    = (const float*)d_in[0];
    const float* xi    = (const float*)d_in[1];
    const float* angle = (const float*)d_in[2];
    float* out = (float*)d_out;

    unsigned int n = (unsigned int)in_sizes[0];   // N = 2^23 complex elements
    unsigned int n4 = n / 4u;                     // float4 chunks
    unsigned int block = 256u;
    unsigned int grid = 2048u;                    // G11: cap + grid-stride

    crx_real_kernel<<<grid, block, 0, stream>>>(xr, xi, angle, out, n4);
}

// Round 7
// 17.154 us; speedup vs baseline: 1.0735x; 1.0315x over previous
//
#include <hip/hip_runtime.h>

// Controlled target rotation, D=2, control=qubit0 (mask N/2), target=qubit1 (mask N/4).
// Output buffer: N float32 = REAL part of the complex64 state.
//   control clear (i < N/2): out[i] = xr[i]
//   control set:             out[i] = c*xr[i] + s*xi[i ^ (N/4)]
//   c = cos(a/2), s = sin(a/2), a = angle[0].
// Batch-4 per thread, all loads issued before any store -> MLP 4-8 per thread.

typedef float fvec4 __attribute__((ext_vector_type(4)));

__global__ __launch_bounds__(256) void crx_real_kernel(
    const float* __restrict__ xr,
    const float* __restrict__ xi,
    const float* __restrict__ angle,
    float* __restrict__ out,   // N float32 (real part)
    unsigned int n4)           // number of float4 chunks = N/4
{
    const unsigned int cmask4 = n4 >> 1;   // control-bit mask, float4 units
    const unsigned int tmask4 = n4 >> 2;   // target-bit mask, float4 units

    const fvec4* xr4 = reinterpret_cast<const fvec4*>(xr);
    const fvec4* xi4 = reinterpret_cast<const fvec4*>(xi);
    fvec4* out4 = reinterpret_cast<fvec4*>(out);

    // Each block covers 1024 consecutive chunks: thread t handles
    // base+0, +256, +512, +768. Block range stays inside one quarter
    // (quarter = n4/4 = 2^19 chunks) -> control branch is block-uniform.
    unsigned int base = blockIdx.x * 1024u + threadIdx.x;

    fvec4 v0 = __builtin_nontemporal_load(xr4 + base);
    fvec4 v1 = __builtin_nontemporal_load(xr4 + base + 256u);
    fvec4 v2 = __builtin_nontemporal_load(xr4 + base + 512u);
    fvec4 v3 = __builtin_nontemporal_load(xr4 + base + 768u);

    if (base & cmask4) {   // upper half: rotate with partner imag
        fvec4 p0 = __builtin_nontemporal_load(xi4 + ((base)          ^ tmask4));
        fvec4 p1 = __builtin_nontemporal_load(xi4 + ((base + 256u)   ^ tmask4));
        fvec4 p2 = __builtin_nontemporal_load(xi4 + ((base + 512u)   ^ tmask4));
        fvec4 p3 = __builtin_nontemporal_load(xi4 + ((base + 768u)   ^ tmask4));

        float half_a = 0.5f * angle[0];
        float s = sinf(half_a);
        float c = cosf(half_a);

        v0 = c * v0 + s * p0;
        v1 = c * v1 + s * p1;
        v2 = c * v2 + s * p2;
        v3 = c * v3 + s * p3;
    }

    __builtin_nontemporal_store(v0, out4 + base);
    __builtin_nontemporal_store(v1, out4 + base + 256u);
    __builtin_nontemporal_store(v2, out4 + base + 512u);
    __builtin_nontemporal_store(v3, out4 + base + 768u);
}

extern "C" void kernel_launch(void* const* d_in, const int* in_sizes, int n_in,
                              void* d_out, int out_size, void* d_ws, size_t ws_size,
                              hipStream_t stream) {
    const float* xr    = (const float*)d_in[0];
    const float* xi    = (const float*)d_in[1];
    const float* angle = (const float*)d_in[2];
    float* out = (float*)d_out;

    unsigned int n = (unsigned int)in_sizes[0];   // N = 2^23 complex elements
    unsigned int n4 = n / 4u;                     // float4 chunks
    unsigned int block = 256u;
    unsigned int grid = n4 / 1024u;               // exact cover: 2048 blocks
    crx_real_kernel<<<grid, block, 0, stream>>>(xr, xi, angle, out, n4);
}